// Round 1
// baseline (846.426 us; speedup 1.0000x reference)
//
#include <hip/hip_runtime.h>
#include <hip/hip_bf16.h>
#include <math.h>

// Dims (fixed by setup_inputs): S=512, H=4, W=4, D=512, dff=2048, NH=8, depth=64
// Matrix view: M = S*H*W = 8192 rows, D = 512 cols.
//
// Pipeline:
//  1. q = x @ Wq^T + pe           (8192x512x512 GEMM, PE epilogue)
//  2. per (hw,i) group g in [0,128): rs[j] = sum_d q[hw*512+j, i*64+d];
//     a = softmax(rs); ctx[g,d] = sum_m a[m]*q[hw*512+m, i*64+d]
//  3. adist[g,n] = sum_{jm,d} ctx[g,d]*Wfc[n, jm*64+d]   (128 distinct rows)
//  4. o1 = LN(x + adist[g(row)])  g(row) = (row/512)*8 + (row%512)/64
//  5. h1 = relu(o1 @ W1^T + b1)   (8192x2048x512)
//  6. f  = h1 @ W2^T + b2 -> d_out (8192x512x2048)
//  7. d_out = LN(o1 + f)

#define LN10K_OVER_256 0.03597789207803197f

template<int MODE> // 0: +PE (q), 1: relu(+bias), 2: +bias
__global__ __launch_bounds__(256) void gemm_abt(
    const float* __restrict__ A, const float* __restrict__ B,
    const float* __restrict__ bias, float* __restrict__ C,
    int M, int N, int K) {
  const int BM = 64, BN = 64, BK = 16;
  __shared__ float As[BK][BM + 1];
  __shared__ float Bs[BK][BN + 1];
  int t = threadIdx.x;
  int tx = t & 15, ty = t >> 4;
  int m0 = blockIdx.y * BM, n0 = blockIdx.x * BN;
  float acc[4][4] = {};
  for (int k0 = 0; k0 < K; k0 += BK) {
#pragma unroll
    for (int l = 0; l < 4; ++l) {
      int idx = t + l * 256;
      int m = idx >> 4, k = idx & 15;
      As[k][m] = A[(size_t)(m0 + m) * K + k0 + k];
      Bs[k][m] = B[(size_t)(n0 + m) * K + k0 + k];
    }
    __syncthreads();
#pragma unroll
    for (int kk = 0; kk < BK; ++kk) {
      float a[4], b[4];
#pragma unroll
      for (int i = 0; i < 4; ++i) a[i] = As[kk][ty * 4 + i];
#pragma unroll
      for (int j = 0; j < 4; ++j) b[j] = Bs[kk][tx * 4 + j];
#pragma unroll
      for (int i = 0; i < 4; ++i)
#pragma unroll
        for (int j = 0; j < 4; ++j) acc[i][j] += a[i] * b[j];
    }
    __syncthreads();
  }
#pragma unroll
  for (int i = 0; i < 4; ++i) {
    int row = m0 + ty * 4 + i;
#pragma unroll
    for (int j = 0; j < 4; ++j) {
      int col = n0 + tx * 4 + j;
      float v = acc[i][j];
      if (MODE == 0) {
        int s = row >> 4;          // sequence position
        int kk2 = col >> 1;        // pe frequency index
        float div = expf(-(float)kk2 * LN10K_OVER_256);
        float ang = (float)s * div;
        v += (col & 1) ? cosf(ang) : sinf(ang);
      } else if (MODE == 1) {
        v = fmaxf(v + bias[col], 0.f);
      } else {
        v = v + bias[col];
      }
      C[(size_t)row * N + col] = v;
    }
  }
}

// One block per group g = hw*8 + i (128 groups), 256 threads.
__global__ __launch_bounds__(256) void attn_small(const float* __restrict__ q,
                                                  float* __restrict__ ctx) {
  int g = blockIdx.x;
  int hw = g >> 3, i = g & 7;
  const float* base = q + (size_t)hw * (512 * 512) + (size_t)i * 64;
  __shared__ float rs[512];
  __shared__ float red[16];
  __shared__ float pctx[4][64];
  int t = threadIdx.x;
  for (int j = t; j < 512; j += 256) {
    const float* rp = base + (size_t)j * 512;
    float s = 0.f;
#pragma unroll
    for (int d = 0; d < 64; ++d) s += rp[d];
    rs[j] = s;
  }
  __syncthreads();
  // block max over 512
  float m = fmaxf(rs[t], rs[t + 256]);
  for (int off = 32; off; off >>= 1) m = fmaxf(m, __shfl_down(m, off));
  int wid = t >> 6, lane = t & 63;
  if (lane == 0) red[wid] = m;
  __syncthreads();
  if (t == 0) red[8] = fmaxf(fmaxf(red[0], red[1]), fmaxf(red[2], red[3]));
  __syncthreads();
  float M = red[8];
  float e0 = expf(rs[t] - M), e1 = expf(rs[t + 256] - M);
  float s = e0 + e1;
  for (int off = 32; off; off >>= 1) s += __shfl_down(s, off);
  __syncthreads();  // everyone done reading red[8]
  if (lane == 0) red[wid] = s;
  __syncthreads();
  if (t == 0) red[8] = red[0] + red[1] + red[2] + red[3];
  __syncthreads();
  float inv = 1.f / red[8];
  rs[t] = e0 * inv;
  rs[t + 256] = e1 * inv;
  __syncthreads();
  // ctx[d] = sum_m rs[m] * base[m*512 + d]
  int d = t & 63, seg = t >> 6;
  float acc = 0.f;
  for (int mm = seg * 128; mm < seg * 128 + 128; ++mm)
    acc += rs[mm] * base[(size_t)mm * 512 + d];
  pctx[seg][d] = acc;
  __syncthreads();
  if (t < 64)
    ctx[(size_t)g * 64 + t] = pctx[0][t] + pctx[1][t] + pctx[2][t] + pctx[3][t];
}

// adist[g, n] = sum_{c2} ctx[g, c2 & 63] * Wfc[n, c2]
__global__ __launch_bounds__(256) void attn_proj(const float* __restrict__ ctx,
                                                 const float* __restrict__ Wfc,
                                                 float* __restrict__ adist) {
  int g = blockIdx.x;
  __shared__ float c[64];
  int t = threadIdx.x;
  if (t < 64) c[t] = ctx[(size_t)g * 64 + t];
  __syncthreads();
  for (int n = t; n < 512; n += 256) {
    const float* wr = Wfc + (size_t)n * 512;
    float s = 0.f;
#pragma unroll 8
    for (int c2 = 0; c2 < 512; ++c2) s += c[c2 & 63] * wr[c2];
    adist[(size_t)g * 512 + n] = s;
  }
}

// LN over D=512. groupedAdd: Yadd row is adist[(r/512)*8 + (r%512)/64].
__global__ __launch_bounds__(256) void ln_kernel(
    const float* __restrict__ X, const float* __restrict__ Yadd,
    const float* __restrict__ gamma, const float* __restrict__ beta,
    float* __restrict__ Out, int groupedAdd) {
  int r = blockIdx.x;
  int t = threadIdx.x;
  const float* xr = X + (size_t)r * 512;
  const float* yr;
  if (groupedAdd) {
    int g = ((r >> 9) << 3) + ((r & 511) >> 6);
    yr = Yadd + (size_t)g * 512;
  } else {
    yr = Yadd + (size_t)r * 512;
  }
  float v0 = xr[t] + yr[t];
  float v1 = xr[t + 256] + yr[t + 256];
  float s = v0 + v1, sq = v0 * v0 + v1 * v1;
  __shared__ float red[9];
  for (int off = 32; off; off >>= 1) {
    s += __shfl_down(s, off);
    sq += __shfl_down(sq, off);
  }
  int wid = t >> 6, lane = t & 63;
  __shared__ float red2[8];
  if (lane == 0) { red[wid] = s; red2[wid] = sq; }
  __syncthreads();
  if (t == 0) {
    float S = red[0] + red[1] + red[2] + red[3];
    float Q = red2[0] + red2[1] + red2[2] + red2[3];
    float mean = S * (1.f / 512.f);
    float var = Q * (1.f / 512.f) - mean * mean;
    red[4] = mean;
    red[5] = rsqrtf(var + 1e-5f);
  }
  __syncthreads();
  float mean = red[4], inv = red[5];
  Out[(size_t)r * 512 + t]       = (v0 - mean) * inv * gamma[t] + beta[t];
  Out[(size_t)r * 512 + t + 256] = (v1 - mean) * inv * gamma[t + 256] + beta[t + 256];
}

extern "C" void kernel_launch(void* const* d_in, const int* in_sizes, int n_in,
                              void* d_out, int out_size, void* d_ws, size_t ws_size,
                              hipStream_t stream) {
  const float* x   = (const float*)d_in[0];
  const float* Wq  = (const float*)d_in[1];
  const float* Wfc = (const float*)d_in[2];
  const float* W1  = (const float*)d_in[3];
  const float* b1  = (const float*)d_in[4];
  const float* W2  = (const float*)d_in[5];
  const float* b2  = (const float*)d_in[6];
  const float* g1  = (const float*)d_in[7];
  const float* be1 = (const float*)d_in[8];
  const float* g2  = (const float*)d_in[9];
  const float* be2 = (const float*)d_in[10];
  float* out = (float*)d_out;

  float* ws    = (float*)d_ws;
  float* q     = ws;                 // 4,194,304 floats
  float* o1    = ws + 4194304;       // 4,194,304
  float* h1    = ws + 8388608;       // 16,777,216
  float* ctx   = ws + 25165824;      // 8,192
  float* adist = ws + 25174016;      // 65,536  (end: 25,239,552 floats = 96.3 MB)

  // 1. q = x @ Wq^T + pe
  gemm_abt<0><<<dim3(512 / 64, 8192 / 64), 256, 0, stream>>>(
      x, Wq, nullptr, q, 8192, 512, 512);
  // 2. softmax-of-rowsums context per 128 groups
  attn_small<<<128, 256, 0, stream>>>(q, ctx);
  // 3. 128 distinct projected rows
  attn_proj<<<128, 256, 0, stream>>>(ctx, Wfc, adist);
  // 4. o1 = LN(x + attn_out)
  ln_kernel<<<8192, 256, 0, stream>>>(x, adist, g1, be1, o1, 1);
  // 5. h1 = relu(o1 @ W1^T + b1)
  gemm_abt<1><<<dim3(2048 / 64, 8192 / 64), 256, 0, stream>>>(
      o1, W1, b1, h1, 8192, 2048, 512);
  // 6. f = h1 @ W2^T + b2  -> d_out (scratch use)
  gemm_abt<2><<<dim3(512 / 64, 8192 / 64), 256, 0, stream>>>(
      h1, W2, b2, out, 8192, 512, 2048);
  // 7. d_out = LN(o1 + f)  (in-place per row, safe)
  ln_kernel<<<8192, 256, 0, stream>>>(o1, out, g2, be2, out, 0);
}

// Round 2
// 157.113 us; speedup vs baseline: 5.3874x; 5.3874x over previous
//
#include <hip/hip_runtime.h>
#include <hip/hip_bf16.h>
#include <math.h>

// Dims fixed: S=512, H=4, W=4, D=512, dff=2048, NH=8, depth=64. M = 8192 rows.
//
// Pipeline (bf16 MFMA for the 3 GEMMs, fp32 elsewhere):
//  0. cvt x,Wq,W1,W2 -> bf16
//  1. q = xb @ Wqb^T + pe          (MFMA, fp32 out)
//  2. attn_small: softmax-of-rowsums context per 128 groups (fp32)
//  3. wfc_fold + attn_proj2: adist[g,:] (128 distinct rows)
//  4. o1 = LN(x + adist[g(row)])   -> fp32 o1 + bf16 o1b
//  5. h1b = relu(o1b @ W1b^T + b1) (MFMA, bf16 out)
//  6. f  = h1b @ W2b^T + b2 -> d_out fp32 (MFMA)
//  7. d_out = LN(o1 + f)

typedef short short8 __attribute__((ext_vector_type(8)));
typedef float f32x4 __attribute__((ext_vector_type(4)));

#define LN10K_OVER_256 0.03597789207803197f

__device__ __forceinline__ void gload16(const short* g, short* l) {
  __builtin_amdgcn_global_load_lds(
      (const __attribute__((address_space(1))) void*)g,
      (__attribute__((address_space(3))) void*)l, 16, 0, 0);
}

__global__ __launch_bounds__(256) void cvt_bf16(const float* __restrict__ in,
                                                short* __restrict__ out, int n8) {
  int i = blockIdx.x * 256 + threadIdx.x;
  if (i >= n8) return;
  const float4* p = (const float4*)(in + (size_t)i * 8);
  float4 a = p[0], b = p[1];
  union { __hip_bfloat16 h[8]; short8 s; } u;
  u.h[0] = __float2bfloat16(a.x); u.h[1] = __float2bfloat16(a.y);
  u.h[2] = __float2bfloat16(a.z); u.h[3] = __float2bfloat16(a.w);
  u.h[4] = __float2bfloat16(b.x); u.h[5] = __float2bfloat16(b.y);
  u.h[6] = __float2bfloat16(b.z); u.h[7] = __float2bfloat16(b.w);
  *(short8*)(out + (size_t)i * 8) = u.s;
}

// C = A(MxK) @ B(NxK)^T, 128x128 tile, BK=32, 4 waves 2x2, 16x16x32 bf16 MFMA.
// MODE 0: +PE -> fp32 Cf.  MODE 1: relu(+bias) -> bf16 Cb.  MODE 2: +bias -> fp32 Cf.
template<int MODE>
__global__ __launch_bounds__(256) void gemm_mfma(
    const short* __restrict__ A, const short* __restrict__ B,
    const float* __restrict__ bias, float* __restrict__ Cf,
    short* __restrict__ Cb, int M, int N, int K) {
  __shared__ short As[128][32];
  __shared__ short Bs[128][32];
  int t = threadIdx.x;
  int w = t >> 6, l = t & 63;
  int m0 = blockIdx.y * 128, n0 = blockIdx.x * 128;
  int wm = (w >> 1) * 64, wn = (w & 1) * 64;
  f32x4 acc[4][4] = {};
  int srow = w * 32 + (l >> 2);
  int scol = (l & 3) * 8;
  const short* Ag = A + (size_t)(m0 + srow) * K + scol;
  const short* Bg = B + (size_t)(n0 + srow) * K + scol;
  short* Al0 = &As[w * 32][0];
  short* Al1 = &As[w * 32 + 16][0];
  short* Bl0 = &Bs[w * 32][0];
  short* Bl1 = &Bs[w * 32 + 16][0];
  int fr = l & 15, fq = l >> 4;
  for (int k0 = 0; k0 < K; k0 += 32) {
    __syncthreads();  // previous compute done before LDS overwrite
    gload16(Ag, Al0);
    gload16(Ag + (size_t)16 * K, Al1);
    gload16(Bg, Bl0);
    gload16(Bg + (size_t)16 * K, Bl1);
    Ag += 32; Bg += 32;
    __syncthreads();  // staging visible (compiler drains vmcnt before barrier)
    short8 af[4], bf[4];
#pragma unroll
    for (int m = 0; m < 4; ++m)
      af[m] = *(const short8*)&As[wm + m * 16 + fr][fq * 8];
#pragma unroll
    for (int n = 0; n < 4; ++n)
      bf[n] = *(const short8*)&Bs[wn + n * 16 + fr][fq * 8];
#pragma unroll
    for (int m = 0; m < 4; ++m)
#pragma unroll
      for (int n = 0; n < 4; ++n)
        acc[m][n] = __builtin_amdgcn_mfma_f32_16x16x32_bf16(af[m], bf[n],
                                                            acc[m][n], 0, 0, 0);
  }
#pragma unroll
  for (int m = 0; m < 4; ++m) {
#pragma unroll
    for (int n = 0; n < 4; ++n) {
      f32x4 v = acc[m][n];
#pragma unroll
      for (int j = 0; j < 4; ++j) {
        int row = m0 + wm + m * 16 + fq * 4 + j;
        int col = n0 + wn + n * 16 + fr;
        float val = v[j];
        if (MODE == 0) {
          int s = row >> 4;
          float f = expf(-(float)(col >> 1) * LN10K_OVER_256);
          float ang = (float)s * f;
          val += (col & 1) ? cosf(ang) : sinf(ang);
          Cf[(size_t)row * N + col] = val;
        } else if (MODE == 1) {
          val = fmaxf(val + bias[col], 0.f);
          __hip_bfloat16 hb = __float2bfloat16(val);
          Cb[(size_t)row * N + col] = *(short*)&hb;
        } else {
          Cf[(size_t)row * N + col] = val + bias[col];
        }
      }
    }
  }
}

// One block per group g = hw*8 + i (128 groups).
__global__ __launch_bounds__(256) void attn_small(const float* __restrict__ q,
                                                  float* __restrict__ ctx) {
  int g = blockIdx.x;
  int hw = g >> 3, i = g & 7;
  const float* base = q + (size_t)hw * (512 * 512) + (size_t)i * 64;
  __shared__ float rs[512];
  __shared__ float red[9];
  __shared__ float red2[8];
  __shared__ float pctx[4][64];
  int t = threadIdx.x;
  for (int j = t; j < 512; j += 256) {
    const float* rp = base + (size_t)j * 512;
    float s = 0.f;
#pragma unroll
    for (int d = 0; d < 64; ++d) s += rp[d];
    rs[j] = s;
  }
  __syncthreads();
  float m = fmaxf(rs[t], rs[t + 256]);
  for (int off = 32; off; off >>= 1) m = fmaxf(m, __shfl_down(m, off));
  int wid = t >> 6, lane = t & 63;
  if (lane == 0) red[wid] = m;
  __syncthreads();
  if (t == 0) red[8] = fmaxf(fmaxf(red[0], red[1]), fmaxf(red[2], red[3]));
  __syncthreads();
  float M = red[8];
  float e0 = expf(rs[t] - M), e1 = expf(rs[t + 256] - M);
  float s = e0 + e1;
  for (int off = 32; off; off >>= 1) s += __shfl_down(s, off);
  __syncthreads();
  if (lane == 0) red[wid] = s;
  __syncthreads();
  if (t == 0) red[8] = red[0] + red[1] + red[2] + red[3];
  __syncthreads();
  float inv = 1.f / red[8];
  rs[t] = e0 * inv;
  rs[t + 256] = e1 * inv;
  __syncthreads();
  int d = t & 63, seg = t >> 6;
  float acc = 0.f;
  for (int mm = seg * 128; mm < seg * 128 + 128; ++mm)
    acc += rs[mm] * base[(size_t)mm * 512 + d];
  pctx[seg][d] = acc;
  __syncthreads();
  if (t < 64)
    ctx[(size_t)g * 64 + t] = pctx[0][t] + pctx[1][t] + pctx[2][t] + pctx[3][t];
}

// wsum[n,d] = sum_j Wfc[n, j*64+d]  (reads Wfc exactly once)
__global__ __launch_bounds__(256) void wfc_fold(const float* __restrict__ Wfc,
                                                float* __restrict__ wsum) {
  int idx = blockIdx.x * 256 + threadIdx.x;  // 512*64 = 32768
  int n = idx >> 6, d = idx & 63;
  float s = 0.f;
#pragma unroll
  for (int j = 0; j < 8; ++j) s += Wfc[(size_t)n * 512 + j * 64 + d];
  wsum[idx] = s;
}

__global__ __launch_bounds__(256) void attn_proj2(const float* __restrict__ ctx,
                                                  const float* __restrict__ wsum,
                                                  float* __restrict__ adist) {
  int g = blockIdx.x;
  __shared__ float c[64];
  int t = threadIdx.x;
  if (t < 64) c[t] = ctx[(size_t)g * 64 + t];
  __syncthreads();
  for (int n = t; n < 512; n += 256) {
    const float* wr = wsum + (size_t)n * 64;
    float s = 0.f;
#pragma unroll
    for (int d = 0; d < 64; ++d) s += c[d] * wr[d];
    adist[(size_t)g * 512 + n] = s;
  }
}

// LN over D=512; optional grouped residual row; optional extra bf16 output.
__global__ __launch_bounds__(256) void ln_kernel(
    const float* __restrict__ X, const float* __restrict__ Yadd,
    const float* __restrict__ gamma, const float* __restrict__ beta,
    float* __restrict__ Out, short* __restrict__ OutB, int groupedAdd) {
  int r = blockIdx.x;
  int t = threadIdx.x;
  const float* xr = X + (size_t)r * 512;
  const float* yr;
  if (groupedAdd) {
    int g = ((r >> 9) << 3) + ((r & 511) >> 6);
    yr = Yadd + (size_t)g * 512;
  } else {
    yr = Yadd + (size_t)r * 512;
  }
  float v0 = xr[t] + yr[t];
  float v1 = xr[t + 256] + yr[t + 256];
  float s = v0 + v1, sq = v0 * v0 + v1 * v1;
  __shared__ float red[6];
  __shared__ float redA[4];
  __shared__ float redB[4];
  for (int off = 32; off; off >>= 1) {
    s += __shfl_down(s, off);
    sq += __shfl_down(sq, off);
  }
  int wid = t >> 6, lane = t & 63;
  if (lane == 0) { redA[wid] = s; redB[wid] = sq; }
  __syncthreads();
  if (t == 0) {
    float S = redA[0] + redA[1] + redA[2] + redA[3];
    float Q = redB[0] + redB[1] + redB[2] + redB[3];
    float mean = S * (1.f / 512.f);
    float var = Q * (1.f / 512.f) - mean * mean;
    red[4] = mean;
    red[5] = rsqrtf(var + 1e-5f);
  }
  __syncthreads();
  float mean = red[4], inv = red[5];
  float r0 = (v0 - mean) * inv * gamma[t] + beta[t];
  float r1 = (v1 - mean) * inv * gamma[t + 256] + beta[t + 256];
  Out[(size_t)r * 512 + t] = r0;
  Out[(size_t)r * 512 + t + 256] = r1;
  if (OutB) {
    __hip_bfloat16 h0 = __float2bfloat16(r0);
    __hip_bfloat16 h1 = __float2bfloat16(r1);
    OutB[(size_t)r * 512 + t] = *(short*)&h0;
    OutB[(size_t)r * 512 + t + 256] = *(short*)&h1;
  }
}

extern "C" void kernel_launch(void* const* d_in, const int* in_sizes, int n_in,
                              void* d_out, int out_size, void* d_ws, size_t ws_size,
                              hipStream_t stream) {
  const float* x   = (const float*)d_in[0];
  const float* Wq  = (const float*)d_in[1];
  const float* Wfc = (const float*)d_in[2];
  const float* W1  = (const float*)d_in[3];
  const float* b1  = (const float*)d_in[4];
  const float* W2  = (const float*)d_in[5];
  const float* b2  = (const float*)d_in[6];
  const float* g1  = (const float*)d_in[7];
  const float* be1 = (const float*)d_in[8];
  const float* g2  = (const float*)d_in[9];
  const float* be2 = (const float*)d_in[10];
  float* out = (float*)d_out;

  char* ws = (char*)d_ws;
  float* q     = (float*)(ws);                       // 16 MB
  float* o1    = (float*)(ws + (16u << 20));         // 16 MB
  float* ctx   = (float*)(ws + (32u << 20));         // 32 KB
  float* adist = (float*)(ws + (32u << 20) + (64u << 10));   // 256 KB
  float* wsum  = (float*)(ws + (32u << 20) + (384u << 10));  // 128 KB
  short* xb    = (short*)(ws + (33u << 20));         // 8 MB
  short* Wqb   = (short*)(ws + (41u << 20));         // 0.5 MB
  short* W1b   = (short*)(ws + (42u << 20));         // 2 MB
  short* W2b   = (short*)(ws + (44u << 20));         // 2 MB
  short* o1b   = (short*)(ws + (46u << 20));         // 8 MB
  short* h1b   = (short*)(ws + (54u << 20));         // 32 MB (end 86 MB)

  // 0. conversions
  cvt_bf16<<<2048, 256, 0, stream>>>(x, xb, 524288);
  cvt_bf16<<<128, 256, 0, stream>>>(Wq, Wqb, 32768);
  cvt_bf16<<<512, 256, 0, stream>>>(W1, W1b, 131072);
  cvt_bf16<<<512, 256, 0, stream>>>(W2, W2b, 131072);
  // 1. q = xb @ Wqb^T + pe
  gemm_mfma<0><<<dim3(4, 64), 256, 0, stream>>>(xb, Wqb, nullptr, q, nullptr,
                                                8192, 512, 512);
  // 2. context per group
  attn_small<<<128, 256, 0, stream>>>(q, ctx);
  // 3. projection via folded Wfc
  wfc_fold<<<128, 256, 0, stream>>>(Wfc, wsum);
  attn_proj2<<<128, 256, 0, stream>>>(ctx, wsum, adist);
  // 4. o1 = LN(x + attn) -> fp32 + bf16
  ln_kernel<<<8192, 256, 0, stream>>>(x, adist, g1, be1, o1, o1b, 1);
  // 5. h1b = relu(o1b @ W1b^T + b1)
  gemm_mfma<1><<<dim3(16, 64), 256, 0, stream>>>(o1b, W1b, b1, nullptr, h1b,
                                                 8192, 2048, 512);
  // 6. f = h1b @ W2b^T + b2 -> out (fp32)
  gemm_mfma<2><<<dim3(4, 64), 256, 0, stream>>>(h1b, W2b, b2, out, nullptr,
                                                8192, 512, 2048);
  // 7. d_out = LN(o1 + f), in place per row
  ln_kernel<<<8192, 256, 0, stream>>>(o1, out, g2, be2, out, nullptr, 0);
}

// Round 3
// 128.761 us; speedup vs baseline: 6.5736x; 1.2202x over previous
//
#include <hip/hip_runtime.h>
#include <hip/hip_bf16.h>
#include <math.h>

// Dims fixed: S=512, H=4, W=4, D=512, dff=2048, NH=8, depth=64. M = 8192 rows.
//
// Pipeline:
//  0. cvt x,Wq,W1,W2 -> bf16
//  1. q = xb @ Wqb^T + pe          (m97-style 128x128 MFMA kernel)
//  2. attn_small: softmax-of-rowsums context per 128 groups
//  3. wfc_fold + attn_proj2: adist (128 distinct rows)
//  4. o1 = LN(x + adist[g(row)])   -> fp32 o1 + bf16 o1b
//  5. h1b = relu(o1b @ W1b^T + b1)  gemm256 pipelined (MODE 1)
//  6. FFN2 split-K=4: partial[z] = h1b[:, z*512:+512] @ W2b[:, z*512:+512]^T (bf16, MODE 3)
//  7. d_out = LN(o1 + sum_z partial[z] + b2)   (ln2_fused)

typedef short short8 __attribute__((ext_vector_type(8)));
typedef float f32x4 __attribute__((ext_vector_type(4)));

#define LN10K_OVER_256 0.03597789207803197f

__device__ __forceinline__ void gload16(const short* g, short* l) {
  __builtin_amdgcn_global_load_lds(
      (const __attribute__((address_space(1))) void*)g,
      (__attribute__((address_space(3))) void*)l, 16, 0, 0);
}

#define BAR() do { asm volatile("" ::: "memory"); \
                   __builtin_amdgcn_s_barrier();  \
                   asm volatile("" ::: "memory"); } while (0)

// paired-row swizzled LDS read: conceptual [256 rows][32 cols] bf16 per op-buffer,
// physical super-row = 2 rows (128B = 8 slots of 16B), slot ^= (super_row & 7).
__device__ __forceinline__ short8 ldsfrag(const short* opbuf, int R, int fq) {
  int sr = R >> 1;
  int sp = (((R & 1) << 2) | fq) ^ (sr & 7);
  return *(const short8*)(opbuf + sr * 64 + sp * 8);
}

// ============ 256x256/BK32, 8-wave, 3-deep pipelined bf16 GEMM ============
// C = A(MxK) @ B(NxK)^T over K-range [koff, koff+NT*32).
// MODE 1: relu(acc+bias) -> bf16 C0.  MODE 3: raw -> bf16 C{z} (split-K partial).
template<bool DOSTAGE, int WAITK>
__device__ __forceinline__ void tile_step(
    short* ldsb, int cur, int nx, int tt, int koff,
    const short* Ag0, const short* Ag1, const short* Bg0, const short* Bg1,
    int w, int fr, int fq, int wm, int wn, f32x4 (&acc)[8][4]) {
  const short* Abuf = ldsb + cur * 16384;
  const short* Bbuf = Abuf + 8192;
  short8 af[4], bfr[4];
#pragma unroll
  for (int m = 0; m < 4; ++m) af[m] = ldsfrag(Abuf, wm + m * 16 + fr, fq);
#pragma unroll
  for (int n = 0; n < 4; ++n) bfr[n] = ldsfrag(Bbuf, wn + n * 16 + fr, fq);
  if (DOSTAGE) {
    int kb = koff + (tt + 2) * 32;
    gload16(Ag0 + kb, ldsb + nx * 16384 + w * 512);
    gload16(Ag1 + kb, ldsb + nx * 16384 + 4096 + w * 512);
  }
  BAR();
  __builtin_amdgcn_s_setprio(1);
#pragma unroll
  for (int m = 0; m < 4; ++m)
#pragma unroll
    for (int n = 0; n < 4; ++n)
      acc[m][n] = __builtin_amdgcn_mfma_f32_16x16x32_bf16(af[m], bfr[n],
                                                          acc[m][n], 0, 0, 0);
  __builtin_amdgcn_s_setprio(0);
  BAR();
#pragma unroll
  for (int m = 0; m < 4; ++m) af[m] = ldsfrag(Abuf, wm + 64 + m * 16 + fr, fq);
  if (DOSTAGE) {
    int kb = koff + (tt + 2) * 32;
    gload16(Bg0 + kb, ldsb + nx * 16384 + 8192 + w * 512);
    gload16(Bg1 + kb, ldsb + nx * 16384 + 8192 + 4096 + w * 512);
  }
  BAR();
  __builtin_amdgcn_s_setprio(1);
#pragma unroll
  for (int m = 0; m < 4; ++m)
#pragma unroll
    for (int n = 0; n < 4; ++n)
      acc[4 + m][n] = __builtin_amdgcn_mfma_f32_16x16x32_bf16(af[m], bfr[n],
                                                              acc[4 + m][n], 0, 0, 0);
  __builtin_amdgcn_s_setprio(0);
  if (WAITK == 4) asm volatile("s_waitcnt vmcnt(4)" ::: "memory");
  else if (WAITK == 0) asm volatile("s_waitcnt vmcnt(0)" ::: "memory");
  BAR();
}

template<int MODE, int NT>
__global__ __launch_bounds__(512) void gemm256(
    const short* __restrict__ A, const short* __restrict__ B,
    const float* __restrict__ bias,
    short* __restrict__ C0, short* __restrict__ C1,
    short* __restrict__ C2, short* __restrict__ C3,
    int ldC, int ldA, int ldB) {
  __shared__ short lds[3 * 2 * 8192];  // 96 KiB: 3 bufs x (A 16K + B 16K shorts)
  const int t = threadIdx.x;
  const int w = t >> 6, l = t & 63;
  const int fr = l & 15, fq = l >> 4;
  const int wm = (w >> 2) * 128;   // 2 warp-rows
  const int wn = (w & 3) * 64;     // 4 warp-cols
  const int m0 = blockIdx.y * 256, n0 = blockIdx.x * 256;
  const int z = blockIdx.z;
  const int koff = z * (NT * 32);

  // per-thread staging source coords (pre-swizzled global, rule #21)
  const int scont = (t & 7) ^ ((t >> 3) & 7);
  const int Rbase = ((t >> 3) << 1) | (scont >> 2);
  const int cg = (scont & 3) << 3;
  const short* Ag0 = A + (size_t)(m0 + Rbase) * ldA + cg;
  const short* Ag1 = Ag0 + (size_t)128 * ldA;
  const short* Bg0 = B + (size_t)(n0 + Rbase) * ldB + cg;
  const short* Bg1 = Bg0 + (size_t)128 * ldB;
  short* ldsb = &lds[0];

  // prologue: tile0 -> buf0, tile1 -> buf1 (8 loads/wave); wait tile0 (4 left in flight)
  gload16(Ag0 + koff, ldsb + w * 512);
  gload16(Ag1 + koff, ldsb + 4096 + w * 512);
  gload16(Bg0 + koff, ldsb + 8192 + w * 512);
  gload16(Bg1 + koff, ldsb + 8192 + 4096 + w * 512);
  gload16(Ag0 + koff + 32, ldsb + 16384 + w * 512);
  gload16(Ag1 + koff + 32, ldsb + 16384 + 4096 + w * 512);
  gload16(Bg0 + koff + 32, ldsb + 16384 + 8192 + w * 512);
  gload16(Bg1 + koff + 32, ldsb + 16384 + 8192 + 4096 + w * 512);
  asm volatile("s_waitcnt vmcnt(4)" ::: "memory");
  BAR();

  f32x4 acc[8][4] = {};
  int cur = 0;
#pragma unroll 1
  for (int tt = 0; tt < NT - 2; ++tt) {
    int nx = cur + 2; if (nx >= 3) nx -= 3;
    tile_step<true, 4>(ldsb, cur, nx, tt, koff, Ag0, Ag1, Bg0, Bg1,
                       w, fr, fq, wm, wn, acc);
    if (++cur == 3) cur = 0;
  }
  tile_step<false, 0>(ldsb, cur, 0, NT - 2, koff, Ag0, Ag1, Bg0, Bg1,
                      w, fr, fq, wm, wn, acc);
  { int c2 = cur + 1; if (c2 >= 3) c2 -= 3;
    tile_step<false, -1>(ldsb, c2, 0, NT - 1, koff, Ag0, Ag1, Bg0, Bg1,
                         w, fr, fq, wm, wn, acc); }

  // epilogue
  short* myC;
  if (MODE == 1) myC = C0;
  else myC = (z == 0) ? C0 : (z == 1) ? C1 : (z == 2) ? C2 : C3;
  float bv[4];
  if (MODE == 1) {
#pragma unroll
    for (int n = 0; n < 4; ++n) bv[n] = bias[n0 + wn + n * 16 + fr];
  }
#pragma unroll
  for (int mm = 0; mm < 8; ++mm) {
#pragma unroll
    for (int n = 0; n < 4; ++n) {
      int col = n0 + wn + n * 16 + fr;
#pragma unroll
      for (int j = 0; j < 4; ++j) {
        int row = m0 + wm + mm * 16 + fq * 4 + j;
        float v = acc[mm][n][j];
        if (MODE == 1) v = fmaxf(v + bv[n], 0.f);
        __hip_bfloat16 hb = __float2bfloat16(v);
        myC[(size_t)row * ldC + col] = *(short*)&hb;
      }
    }
  }
}

// ============ supporting kernels (round-2, unchanged where noted) ============

__global__ __launch_bounds__(256) void cvt_bf16(const float* __restrict__ in,
                                                short* __restrict__ out, int n8) {
  int i = blockIdx.x * 256 + threadIdx.x;
  if (i >= n8) return;
  const float4* p = (const float4*)(in + (size_t)i * 8);
  float4 a = p[0], b = p[1];
  union { __hip_bfloat16 h[8]; short8 s; } u;
  u.h[0] = __float2bfloat16(a.x); u.h[1] = __float2bfloat16(a.y);
  u.h[2] = __float2bfloat16(a.z); u.h[3] = __float2bfloat16(a.w);
  u.h[4] = __float2bfloat16(b.x); u.h[5] = __float2bfloat16(b.y);
  u.h[6] = __float2bfloat16(b.z); u.h[7] = __float2bfloat16(b.w);
  *(short8*)(out + (size_t)i * 8) = u.s;
}

// m97-style 128x128 GEMM, MODE 0 only: q = A@B^T + PE -> fp32
__global__ __launch_bounds__(256) void gemm_q(
    const short* __restrict__ A, const short* __restrict__ B,
    float* __restrict__ Cf, int M, int N, int K) {
  __shared__ short As[128][32];
  __shared__ short Bs[128][32];
  int t = threadIdx.x;
  int w = t >> 6, l = t & 63;
  int m0 = blockIdx.y * 128, n0 = blockIdx.x * 128;
  int wm = (w >> 1) * 64, wn = (w & 1) * 64;
  f32x4 acc[4][4] = {};
  int srow = w * 32 + (l >> 2);
  int scol = (l & 3) * 8;
  const short* Ag = A + (size_t)(m0 + srow) * K + scol;
  const short* Bg = B + (size_t)(n0 + srow) * K + scol;
  short* Al0 = &As[w * 32][0];
  short* Al1 = &As[w * 32 + 16][0];
  short* Bl0 = &Bs[w * 32][0];
  short* Bl1 = &Bs[w * 32 + 16][0];
  int fr = l & 15, fq = l >> 4;
  for (int k0 = 0; k0 < K; k0 += 32) {
    __syncthreads();
    gload16(Ag, Al0);
    gload16(Ag + (size_t)16 * K, Al1);
    gload16(Bg, Bl0);
    gload16(Bg + (size_t)16 * K, Bl1);
    Ag += 32; Bg += 32;
    __syncthreads();
    short8 af[4], bf[4];
#pragma unroll
    for (int m = 0; m < 4; ++m)
      af[m] = *(const short8*)&As[wm + m * 16 + fr][fq * 8];
#pragma unroll
    for (int n = 0; n < 4; ++n)
      bf[n] = *(const short8*)&Bs[wn + n * 16 + fr][fq * 8];
#pragma unroll
    for (int m = 0; m < 4; ++m)
#pragma unroll
      for (int n = 0; n < 4; ++n)
        acc[m][n] = __builtin_amdgcn_mfma_f32_16x16x32_bf16(af[m], bf[n],
                                                            acc[m][n], 0, 0, 0);
  }
#pragma unroll
  for (int m = 0; m < 4; ++m) {
#pragma unroll
    for (int n = 0; n < 4; ++n) {
      f32x4 v = acc[m][n];
#pragma unroll
      for (int j = 0; j < 4; ++j) {
        int row = m0 + wm + m * 16 + fq * 4 + j;
        int col = n0 + wn + n * 16 + fr;
        int s = row >> 4;
        float f = expf(-(float)(col >> 1) * LN10K_OVER_256);
        float ang = (float)s * f;
        Cf[(size_t)row * N + col] = v[j] + ((col & 1) ? cosf(ang) : sinf(ang));
      }
    }
  }
}

__global__ __launch_bounds__(256) void attn_small(const float* __restrict__ q,
                                                  float* __restrict__ ctx) {
  int g = blockIdx.x;
  int hw = g >> 3, i = g & 7;
  const float* base = q + (size_t)hw * (512 * 512) + (size_t)i * 64;
  __shared__ float rs[512];
  __shared__ float red[9];
  __shared__ float pctx[4][64];
  int t = threadIdx.x;
  for (int j = t; j < 512; j += 256) {
    const float* rp = base + (size_t)j * 512;
    float s = 0.f;
#pragma unroll
    for (int d = 0; d < 64; ++d) s += rp[d];
    rs[j] = s;
  }
  __syncthreads();
  float m = fmaxf(rs[t], rs[t + 256]);
  for (int off = 32; off; off >>= 1) m = fmaxf(m, __shfl_down(m, off));
  int wid = t >> 6, lane = t & 63;
  if (lane == 0) red[wid] = m;
  __syncthreads();
  if (t == 0) red[8] = fmaxf(fmaxf(red[0], red[1]), fmaxf(red[2], red[3]));
  __syncthreads();
  float M = red[8];
  float e0 = expf(rs[t] - M), e1 = expf(rs[t + 256] - M);
  float s = e0 + e1;
  for (int off = 32; off; off >>= 1) s += __shfl_down(s, off);
  __syncthreads();
  if (lane == 0) red[wid] = s;
  __syncthreads();
  if (t == 0) red[8] = red[0] + red[1] + red[2] + red[3];
  __syncthreads();
  float inv = 1.f / red[8];
  rs[t] = e0 * inv;
  rs[t + 256] = e1 * inv;
  __syncthreads();
  int d = t & 63, seg = t >> 6;
  float acc = 0.f;
  for (int mm = seg * 128; mm < seg * 128 + 128; ++mm)
    acc += rs[mm] * base[(size_t)mm * 512 + d];
  pctx[seg][d] = acc;
  __syncthreads();
  if (t < 64)
    ctx[(size_t)g * 64 + t] = pctx[0][t] + pctx[1][t] + pctx[2][t] + pctx[3][t];
}

__global__ __launch_bounds__(256) void wfc_fold(const float* __restrict__ Wfc,
                                                float* __restrict__ wsum) {
  int idx = blockIdx.x * 256 + threadIdx.x;
  int n = idx >> 6, d = idx & 63;
  float s = 0.f;
#pragma unroll
  for (int j = 0; j < 8; ++j) s += Wfc[(size_t)n * 512 + j * 64 + d];
  wsum[idx] = s;
}

__global__ __launch_bounds__(256) void attn_proj2(const float* __restrict__ ctx,
                                                  const float* __restrict__ wsum,
                                                  float* __restrict__ adist) {
  int g = blockIdx.x;
  __shared__ float c[64];
  int t = threadIdx.x;
  if (t < 64) c[t] = ctx[(size_t)g * 64 + t];
  __syncthreads();
  for (int n = t; n < 512; n += 256) {
    const float* wr = wsum + (size_t)n * 64;
    float s = 0.f;
#pragma unroll
    for (int d = 0; d < 64; ++d) s += c[d] * wr[d];
    adist[(size_t)g * 512 + n] = s;
  }
}

__global__ __launch_bounds__(256) void ln_kernel(
    const float* __restrict__ X, const float* __restrict__ Yadd,
    const float* __restrict__ gamma, const float* __restrict__ beta,
    float* __restrict__ Out, short* __restrict__ OutB, int groupedAdd) {
  int r = blockIdx.x;
  int t = threadIdx.x;
  const float* xr = X + (size_t)r * 512;
  const float* yr;
  if (groupedAdd) {
    int g = ((r >> 9) << 3) + ((r & 511) >> 6);
    yr = Yadd + (size_t)g * 512;
  } else {
    yr = Yadd + (size_t)r * 512;
  }
  float v0 = xr[t] + yr[t];
  float v1 = xr[t + 256] + yr[t + 256];
  float s = v0 + v1, sq = v0 * v0 + v1 * v1;
  __shared__ float red[6];
  __shared__ float redA[4];
  __shared__ float redB[4];
  for (int off = 32; off; off >>= 1) {
    s += __shfl_down(s, off);
    sq += __shfl_down(sq, off);
  }
  int wid = t >> 6, lane = t & 63;
  if (lane == 0) { redA[wid] = s; redB[wid] = sq; }
  __syncthreads();
  if (t == 0) {
    float S = redA[0] + redA[1] + redA[2] + redA[3];
    float Q = redB[0] + redB[1] + redB[2] + redB[3];
    float mean = S * (1.f / 512.f);
    float var = Q * (1.f / 512.f) - mean * mean;
    red[4] = mean;
    red[5] = rsqrtf(var + 1e-5f);
  }
  __syncthreads();
  float mean = red[4], inv = red[5];
  float r0 = (v0 - mean) * inv * gamma[t] + beta[t];
  float r1 = (v1 - mean) * inv * gamma[t + 256] + beta[t + 256];
  Out[(size_t)r * 512 + t] = r0;
  Out[(size_t)r * 512 + t + 256] = r1;
  if (OutB) {
    __hip_bfloat16 h0 = __float2bfloat16(r0);
    __hip_bfloat16 h1 = __float2bfloat16(r1);
    OutB[(size_t)r * 512 + t] = *(short*)&h0;
    OutB[(size_t)r * 512 + t + 256] = *(short*)&h1;
  }
}

// final LN fused with split-K reduce of 4 bf16 partials + b2
__global__ __launch_bounds__(256) void ln2_fused(
    const float* __restrict__ o1,
    const short* __restrict__ p0, const short* __restrict__ p1,
    const short* __restrict__ p2, const short* __restrict__ p3,
    const float* __restrict__ b2, const float* __restrict__ gamma,
    const float* __restrict__ beta, float* __restrict__ Out) {
  int r = blockIdx.x;
  int t = threadIdx.x;
  size_t base = (size_t)r * 512;
  float v[2];
#pragma unroll
  for (int h = 0; h < 2; ++h) {
    int c = t + h * 256;
    float f = b2[c];
    f += __bfloat162float(*(const __hip_bfloat16*)&p0[base + c]);
    f += __bfloat162float(*(const __hip_bfloat16*)&p1[base + c]);
    f += __bfloat162float(*(const __hip_bfloat16*)&p2[base + c]);
    f += __bfloat162float(*(const __hip_bfloat16*)&p3[base + c]);
    v[h] = o1[base + c] + f;
  }
  float s = v[0] + v[1], sq = v[0] * v[0] + v[1] * v[1];
  __shared__ float red[6];
  __shared__ float redA[4];
  __shared__ float redB[4];
  for (int off = 32; off; off >>= 1) {
    s += __shfl_down(s, off);
    sq += __shfl_down(sq, off);
  }
  int wid = t >> 6, lane = t & 63;
  if (lane == 0) { redA[wid] = s; redB[wid] = sq; }
  __syncthreads();
  if (t == 0) {
    float S = redA[0] + redA[1] + redA[2] + redA[3];
    float Q = redB[0] + redB[1] + redB[2] + redB[3];
    float mean = S * (1.f / 512.f);
    float var = Q * (1.f / 512.f) - mean * mean;
    red[4] = mean;
    red[5] = rsqrtf(var + 1e-5f);
  }
  __syncthreads();
  float mean = red[4], inv = red[5];
  Out[base + t] = (v[0] - mean) * inv * gamma[t] + beta[t];
  Out[base + t + 256] = (v[1] - mean) * inv * gamma[t + 256] + beta[t + 256];
}

extern "C" void kernel_launch(void* const* d_in, const int* in_sizes, int n_in,
                              void* d_out, int out_size, void* d_ws, size_t ws_size,
                              hipStream_t stream) {
  const float* x   = (const float*)d_in[0];
  const float* Wq  = (const float*)d_in[1];
  const float* Wfc = (const float*)d_in[2];
  const float* W1  = (const float*)d_in[3];
  const float* b1  = (const float*)d_in[4];
  const float* W2  = (const float*)d_in[5];
  const float* b2  = (const float*)d_in[6];
  const float* g1  = (const float*)d_in[7];
  const float* be1 = (const float*)d_in[8];
  const float* g2  = (const float*)d_in[9];
  const float* be2 = (const float*)d_in[10];
  float* out = (float*)d_out;

  char* ws = (char*)d_ws;
  float* q     = (float*)(ws);                       // 16 MB (dead after attn_small)
  float* o1    = (float*)(ws + (16u << 20));         // 16 MB
  float* ctx   = (float*)(ws + (32u << 20));
  float* adist = (float*)(ws + (32u << 20) + (64u << 10));
  float* wsum  = (float*)(ws + (32u << 20) + (384u << 10));
  short* xb    = (short*)(ws + (33u << 20));         // 8 MB (dead after gemm_q)
  short* Wqb   = (short*)(ws + (41u << 20));
  short* W1b   = (short*)(ws + (42u << 20));
  short* W2b   = (short*)(ws + (44u << 20));
  short* o1b   = (short*)(ws + (46u << 20));         // 8 MB (dead after FFN1)
  short* h1b   = (short*)(ws + (54u << 20));         // 32 MB (end 86 MB)
  // FFN2 bf16 partials (8 MB each) overlay dead regions:
  short* pz0   = (short*)(ws);                       // over q[0:8MB]
  short* pz1   = (short*)(ws + (8u << 20));          // over q[8:16MB]
  short* pz2   = (short*)(ws + (46u << 20));         // over o1b
  short* pz3   = (short*)(ws + (33u << 20));         // over xb

  // 0. conversions
  cvt_bf16<<<2048, 256, 0, stream>>>(x, xb, 524288);
  cvt_bf16<<<128, 256, 0, stream>>>(Wq, Wqb, 32768);
  cvt_bf16<<<512, 256, 0, stream>>>(W1, W1b, 131072);
  cvt_bf16<<<512, 256, 0, stream>>>(W2, W2b, 131072);
  // 1. q = xb @ Wqb^T + pe
  gemm_q<<<dim3(4, 64), 256, 0, stream>>>(xb, Wqb, q, 8192, 512, 512);
  // 2-3. attention context + projection
  attn_small<<<128, 256, 0, stream>>>(q, ctx);
  wfc_fold<<<128, 256, 0, stream>>>(Wfc, wsum);
  attn_proj2<<<128, 256, 0, stream>>>(ctx, wsum, adist);
  // 4. o1 = LN(x + attn) -> fp32 + bf16
  ln_kernel<<<8192, 256, 0, stream>>>(x, adist, g1, be1, o1, o1b, 1);
  // 5. h1b = relu(o1b @ W1b^T + b1)   [pipelined 256^2]
  gemm256<1, 16><<<dim3(8, 32, 1), 512, 0, stream>>>(
      o1b, W1b, b1, h1b, h1b, h1b, h1b, 2048, 512, 512);
  // 6. FFN2 split-K=4 partials (bf16)
  gemm256<3, 16><<<dim3(2, 32, 4), 512, 0, stream>>>(
      h1b, W2b, nullptr, pz0, pz1, pz2, pz3, 512, 2048, 2048);
  // 7. d_out = LN(o1 + sum partials + b2)
  ln2_fused<<<8192, 256, 0, stream>>>(o1, pz0, pz1, pz2, pz3, b2, g2, be2, out);
}